// Round 9
// baseline (151.679 us; speedup 1.0000x reference)
//
#include <hip/hip_runtime.h>
#include <hip/hip_bf16.h>
#include <cstdint>
#include <cstddef>

#define HW   1024   // H*W tokens
#define NC   512    // channels
#define NB   16     // batch
#define EPSV 1e-5f

typedef __hip_bfloat16 bf16;
typedef __attribute__((ext_vector_type(8))) __bf16 bf16x8;
typedef __attribute__((ext_vector_type(4))) float f32x4;

__device__ __forceinline__ float b2f(bf16 h) { return __bfloat162float(h); }

__device__ __forceinline__ void gload16(const void* g, void* l) {
  __builtin_amdgcn_global_load_lds(
      (const __attribute__((address_space(1))) uint32_t*)g,
      (__attribute__((address_space(3))) uint32_t*)l, 16, 0, 0);
}

// ---------------- weight fp32 -> bf16 convert ----------------
__global__ __launch_bounds__(256) void cvt_w_kernel(
    const float* __restrict__ wi, const float* __restrict__ wo,
    bf16* __restrict__ wib, bf16* __restrict__ wob) {
  int i = blockIdx.x * 256 + threadIdx.x;
  const float4* src;
  bf16* dst;
  int j;
  if (i < 196608) { src = (const float4*)wi; j = i; dst = wib; }
  else            { src = (const float4*)wo; j = i - 196608; dst = wob; }
  float4 v = src[j];
  union { bf16 h[4]; uint2 u; } p;
  p.h[0] = __float2bfloat16(v.x); p.h[1] = __float2bfloat16(v.y);
  p.h[2] = __float2bfloat16(v.z); p.h[3] = __float2bfloat16(v.w);
  *(uint2*)&dst[(size_t)j * 4] = p.u;
}

// ---------------- GroupNorm -> xn token-major bf16 [b][hw][c] ----------------
__global__ __launch_bounds__(256) void gn_kernel(
    const float* __restrict__ x, const float* __restrict__ gamma,
    const float* __restrict__ beta, bf16* __restrict__ xn) {
  int blk = blockIdx.x;
  int b = blk >> 5, g = blk & 31;
  size_t base = ((size_t)(b * NC + g * 16)) * HW;
  const float4* src4 = (const float4*)(x + base);
  int t = threadIdx.x;
  float s = 0.f, ss = 0.f;
  float4 v[16];
#pragma unroll
  for (int i = 0; i < 16; ++i) {
    v[i] = src4[t + i * 256];
    s  += v[i].x + v[i].y + v[i].z + v[i].w;
    ss += v[i].x * v[i].x + v[i].y * v[i].y + v[i].z * v[i].z + v[i].w * v[i].w;
  }
  __shared__ float red[256];
  red[t] = s; __syncthreads();
  for (int o = 128; o > 0; o >>= 1) { if (t < o) red[t] += red[t + o]; __syncthreads(); }
  float mean = red[0] * (1.f / 16384.f);
  __syncthreads();
  red[t] = ss; __syncthreads();
  for (int o = 128; o > 0; o >>= 1) { if (t < o) red[t] += red[t + o]; __syncthreads(); }
  float var = red[0] * (1.f / 16384.f) - mean * mean;
  float rstd = rsqrtf(var + EPSV);

  __shared__ bf16 sm[16][1032];
#pragma unroll
  for (int i = 0; i < 16; ++i) {
    int idx = t + i * 256;
    int c = idx >> 8;
    int hw4 = (idx & 255) * 4;
    float gm = gamma[g * 16 + c], bt = beta[g * 16 + c];
    union { bf16 h[4]; uint2 u; } p;
    p.h[0] = __float2bfloat16((v[i].x - mean) * rstd * gm + bt);
    p.h[1] = __float2bfloat16((v[i].y - mean) * rstd * gm + bt);
    p.h[2] = __float2bfloat16((v[i].z - mean) * rstd * gm + bt);
    p.h[3] = __float2bfloat16((v[i].w - mean) * rstd * gm + bt);
    *(uint2*)&sm[c][hw4] = p.u;
  }
  __syncthreads();
  bf16* dst = xn + (size_t)b * HW * NC + g * 16;
#pragma unroll
  for (int it = 0; it < 8; ++it) {
    int u = it * 256 + t;
    int hw = u >> 1;
    int c8 = (u & 1) * 8;
    union { bf16 h[8]; uint4 q; } p;
#pragma unroll
    for (int j = 0; j < 8; ++j) p.h[j] = sm[c8 + j][hw];
    *(uint4*)&dst[(size_t)hw * NC + c8] = p.q;
  }
}

// ---------------- universal MFMA GEMM: C[M][N] = A[M][K] * B^T[N][K] --------
// MODE 0: bf16 store transposed  C[col*ldc+row], bias[row]        (qk proj)
// MODE 1: bf16 store row-major   C[row*ldc+col], optional bias    (v proj)
template <int MODE>
__global__ __launch_bounds__(256) void gemm_bt(
    const bf16* __restrict__ A, int lda, long long sA,
    const bf16* __restrict__ B, int ldb, long long sB,
    void* __restrict__ Cv, int ldc, long long sC,
    int K,
    const float* __restrict__ bias) {
  __shared__ bf16 sT[2][128][32];
  int z = blockIdx.z;
  const bf16* Ab = A + (size_t)z * sA;
  const bf16* Bb = B + (size_t)z * sB;
  int n0 = blockIdx.x * 128, m0 = blockIdx.y * 128;
  int t = threadIdx.x;
  int l = t & 63, w = t >> 6;
  int wm = w >> 1, wn = w & 1;

  int srow = t >> 2;
  int scol = (t & 3) * 8;

  f32x4 acc[4][4] = {};

  const bf16* ga0 = Ab + (size_t)(m0 + srow) * lda + scol;
  const bf16* gb0 = Bb + (size_t)(n0 + srow) * ldb + scol;

  for (int k0 = 0; k0 < K; k0 += 32) {
    gload16(ga0 + k0, &sT[0][srow][scol]);
    gload16(ga0 + (size_t)64 * lda + k0, &sT[0][64 + srow][scol]);
    gload16(gb0 + k0, &sT[1][srow][scol]);
    gload16(gb0 + (size_t)64 * ldb + k0, &sT[1][64 + srow][scol]);
    __syncthreads();
    bf16x8 af[4], bfr[4];
    int kc = (l >> 4) * 8;
    int ra = wm * 64 + (l & 15);
    int rb = wn * 64 + (l & 15);
#pragma unroll
    for (int i = 0; i < 4; ++i) {
      af[i]  = *(const bf16x8*)&sT[0][ra + i * 16][kc];
      bfr[i] = *(const bf16x8*)&sT[1][rb + i * 16][kc];
    }
#pragma unroll
    for (int i = 0; i < 4; ++i)
#pragma unroll
      for (int j = 0; j < 4; ++j)
        acc[i][j] = __builtin_amdgcn_mfma_f32_16x16x32_bf16(af[i], bfr[j], acc[i][j], 0, 0, 0);
    __syncthreads();
  }

  int rbase = (l >> 4) * 4;
#pragma unroll
  for (int i = 0; i < 4; ++i) {
    int row = m0 + wm * 64 + i * 16 + rbase;
    float4 bv = make_float4(0.f, 0.f, 0.f, 0.f);
    if (MODE == 0) bv = *(const float4*)&bias[row];
    else if (MODE == 1) { if (bias) bv = *(const float4*)&bias[row]; }
#pragma unroll
    for (int j = 0; j < 4; ++j) {
      int col = n0 + wn * 64 + j * 16 + (l & 15);
      if (MODE == 0) {
        bf16* C = (bf16*)Cv + (size_t)z * sC;
        union { bf16 h[4]; uint2 u; } p;
        p.h[0] = __float2bfloat16(acc[i][j][0] + bv.x);
        p.h[1] = __float2bfloat16(acc[i][j][1] + bv.y);
        p.h[2] = __float2bfloat16(acc[i][j][2] + bv.z);
        p.h[3] = __float2bfloat16(acc[i][j][3] + bv.w);
        *(uint2*)&C[(size_t)col * ldc + row] = p.u;
      } else {
        bf16* C = (bf16*)Cv + (size_t)z * sC;
        float bb[4] = {bv.x, bv.y, bv.z, bv.w};
#pragma unroll
        for (int r = 0; r < 4; ++r)
          C[(size_t)(row + r) * ldc + col] = __float2bfloat16(acc[i][j][r] + bb[r]);
      }
    }
  }
}

// ---------------- fused flash attention + out-projection ----------------
// grid: 256 wg, 512 threads (8 waves). KVBLK=64, 16 KV tiles.
// SUBTILED (block-linear) LDS layouts: every operand stored as contiguous
// 1KB blocks [16 rows][64B] matching the MFMA fragment shape, so every
// ds_read_b128 is a sequential 1KB sweep (base + l15*64 + lq*16) -> zero
// read bank conflicts. Staging: linear global_load_lds dest, per-lane source
// decoded from the subtile index (both-sides-or-neither).
__global__ __launch_bounds__(512, 1) void flash_kernel(
    const bf16* __restrict__ qk, const bf16* __restrict__ vcm,
    const bf16* __restrict__ wout, const float* __restrict__ b_out,
    const float* __restrict__ x, float* __restrict__ out) {
  __shared__ char lds[163840];
  char* Qs  = lds;              // 64KB: [ih2 4][ks 16][i_lo 16][64B]
  char* Kb0 = lds + 65536;      // 16KB: [jh 4][k2 4][j_lo 16][64B]
  char* Kb1 = lds + 81920;      // 16KB
  char* Vs  = lds + 98304;      // 64KB: [chh 32][js 2][ch_lo 16][64B]
  char* Wb0 = lds + 65536;      // 32KB (out-proj W dbuf, reuses K bufs)
  char* Wb1 = lds + 98304;      // 32KB (first half of Vs)
  float* redl = (float*)(lds + 131072);  // 1KB (second half of Vs)

  int id = blockIdx.x;
  int xcd = id & 7, rest = id >> 3;
  int q = rest & 15, bh = rest >> 4;
  int b = xcd + bh * 8;         // batch -> fixed XCD (K/V L2 locality)
  int i0 = q * 64;

  const char* qkC = (const char*)qk + (size_t)b * 2097152;  // [1024 tok][1024 ch]
  const char* vC  = (const char*)vcm + (size_t)b * 1048576; // [512 ch][1024 tok]
  const char* wC  = (const char*)wout;                      // [512 co][512 c]

  int t = threadIdx.x, l = t & 63, w = t >> 6;
  int l15 = l & 15, lq = l >> 4;
  int jg = w >> 1, ih = w & 1;  // QK wave role
  int chb = w * 64;             // PV / out-GEMM wave role

  // stage 16KB K chunk for phase p_ (c in [p_*128, p_*128+128)), subtiled
  auto stage_k = [&](int tile_, int p_, char* dst_) {
#pragma unroll
    for (int qq = 0; qq < 2; ++qq) {
      int A = qq * 8192 + t * 16;
      int jh = A >> 12, k2 = (A >> 10) & 3, jlo = (A >> 6) & 15, cb = A & 63;
      gload16(qkC + (size_t)(tile_ * 64 + jh * 16 + jlo) * 2048 + 1024
                  + p_ * 256 + k2 * 64 + cb,
              dst_ + A);
    }
  };
  // stage 8KB of V (ch group v_*64..+64, all 64 j of tile), subtiled
  auto stage_v = [&](int tile_, int v_) {
    int chh = t >> 7, js = (t >> 6) & 1, cl = (t >> 2) & 15, jb = (t & 3) * 16;
    int ch = v_ * 64 + chh * 16 + cl;
    gload16(vC + (size_t)ch * 2048 + tile_ * 128 + js * 64 + jb,
            Vs + v_ * 8192 + t * 16);
  };
  // stage 32KB W chunk (c window kc_*32..+32 channels), subtiled
  auto stage_w = [&](int kc_, char* dst_) {
#pragma unroll
    for (int it = 0; it < 4; ++it) {
      int A = it * 8192 + t * 16;
      int coh = A >> 10, col = (A >> 6) & 15, cb = A & 63;
      gload16(wC + (size_t)(coh * 16 + col) * 1024 + kc_ * 64 + cb, dst_ + A);
    }
  };

  // ---- prologue: stage Q (subtiled) + K chunk 0 of tile 0
  {
#pragma unroll
    for (int it = 0; it < 8; ++it) {
      int A = it * 8192 + t * 16;
      int ih2 = A >> 14, ks = (A >> 10) & 15, ilo = (A >> 6) & 15, cb = A & 63;
      gload16(qkC + (size_t)(i0 + ih2 * 16 + ilo) * 2048 + ks * 64 + cb, Qs + A);
    }
  }
  stage_k(0, 0, Kb0);

  float lacc[2] = {0.f, 0.f};
  f32x4 o[4][4] = {};                       // [mi: ch frag][ni: i frag]
  const float scl = 0.044194173824159216f;  // 1/sqrt(512)

  __syncthreads();   // prologue drain

  for (int tile = 0; tile < 16; ++tile) {
    char* PsBuf = (tile & 1) ? Kb1 : Kb0;   // P overlays the free K buffer
    f32x4 s[2] = {};
#pragma unroll
    for (int p = 0; p < 4; ++p) {
      if (p < 3) {
        char* kd = ((p + 1 + tile) & 1) ? Kb1 : Kb0;
        stage_k(tile, p + 1, kd);
      }
      stage_v(tile, p * 2);
      stage_v(tile, p * 2 + 1);
      const char* kcur = ((p + tile) & 1) ? Kb1 : Kb0;
#pragma unroll
      for (int k2 = 0; k2 < 4; ++k2) {
        bf16x8 kf = *(const bf16x8*)(kcur + jg * 4096 + k2 * 1024 + l15 * 64 + lq * 16);
#pragma unroll
        for (int ni = 0; ni < 2; ++ni) {
          bf16x8 qf = *(const bf16x8*)(Qs + (ih * 2 + ni) * 16384
                        + (p * 4 + k2) * 1024 + l15 * 64 + lq * 16);
          s[ni] = __builtin_amdgcn_mfma_f32_16x16x32_bf16(kf, qf, s[ni], 0, 0, 0);
        }
      }
      __syncthreads();
    }
    // ---- softmax (no max-subtraction) + pack P (subtiled) into free K buf
#pragma unroll
    for (int ni = 0; ni < 2; ++ni) {
      int i = ih * 32 + ni * 16 + l15;      // i = row; (ih*2+ni) = i_hi block
      float p0 = __expf(s[ni][0] * scl);
      float p1 = __expf(s[ni][1] * scl);
      float p2 = __expf(s[ni][2] * scl);
      float p3 = __expf(s[ni][3] * scl);
      lacc[ni] += p0 + p1 + p2 + p3;
      union { bf16 h[4]; uint64_t u; } pk;
      pk.h[0] = __float2bfloat16(p0); pk.h[1] = __float2bfloat16(p1);
      pk.h[2] = __float2bfloat16(p2); pk.h[3] = __float2bfloat16(p3);
      // j = jg*16 + lq*4 + r  ->  js = jg>>1, byte-in-block = (jg&1)*32+lq*8
      int dst = (ih * 2 + ni) * 2048 + (jg >> 1) * 1024 + l15 * 64
              + (jg & 1) * 32 + lq * 8;
      *(uint64_t*)(PsBuf + dst) = pk.u;
      (void)i;
    }
    __syncthreads();  // Ps ready; Vs fully staged
    if (tile < 15) {
      char* kd = ((tile + 1) & 1) ? Kb1 : Kb0;
      stage_k(tile + 1, 0, kd);
    }
#pragma unroll
    for (int ks = 0; ks < 2; ++ks) {
      bf16x8 vf[4];
#pragma unroll
      for (int mi = 0; mi < 4; ++mi)
        vf[mi] = *(const bf16x8*)(Vs + (w * 4 + mi) * 2048 + ks * 1024
                   + l15 * 64 + lq * 16);
#pragma unroll
      for (int ni = 0; ni < 4; ++ni) {
        bf16x8 pf = *(const bf16x8*)(PsBuf + ni * 2048 + ks * 1024
                      + l15 * 64 + lq * 16);
#pragma unroll
        for (int mi = 0; mi < 4; ++mi)
          o[mi][ni] = __builtin_amdgcn_mfma_f32_16x16x32_bf16(vf[mi], pf, o[mi][ni], 0, 0, 0);
      }
    }
    __syncthreads();  // PV done -> next tile may overwrite PsBuf & Vs
  }

  // ---- fused out-projection ----
  stage_w(0, Wb0);   // issue W chunk 0 while combining row sums
#pragma unroll
  for (int ni = 0; ni < 2; ++ni) {
    float v = lacc[ni];
    v += __shfl_xor(v, 16);
    v += __shfl_xor(v, 32);
    if (l < 16) redl[jg * 64 + ih * 32 + ni * 16 + l] = v;
  }
  __syncthreads();  // redl ready; W chunk 0 drained
  float linv[4];
#pragma unroll
  for (int ni = 0; ni < 4; ++ni) {
    int i = ni * 16 + l15;
    linv[ni] = 1.f / (redl[i] + redl[64 + i] + redl[128 + i] + redl[192 + i]);
  }
  // normalized O -> ao_lds subtiled [ih2=ni][kc 16][i_lo 16][64B] over dead Qs
#pragma unroll
  for (int mi = 0; mi < 4; ++mi)
#pragma unroll
    for (int ni = 0; ni < 4; ++ni) {
      union { bf16 h[4]; uint64_t u; } pk;
#pragma unroll
      for (int r = 0; r < 4; ++r)
        pk.h[r] = __float2bfloat16(o[mi][ni][r] * linv[ni]);
      // c = chb + mi*16 + lq*4 + r -> kc = w*2 + (mi>>1), byte = (mi&1)*32+lq*8
      int dst = ni * 16384 + (w * 2 + (mi >> 1)) * 1024 + l15 * 64
              + (mi & 1) * 32 + lq * 8;
      *(uint64_t*)(Qs + dst) = pk.u;
    }
  __syncthreads();  // ao_lds ready

  // GEMM: out[co][i] = sum_c W[co][c] * ao[i][c], K=512 in 16 steps of 32
  f32x4 acc2[4][4] = {};
#pragma unroll
  for (int kc = 0; kc < 16; ++kc) {
    if (kc < 15) stage_w(kc + 1, ((kc + 1) & 1) ? Wb1 : Wb0);
    const char* Wc = (kc & 1) ? Wb1 : Wb0;
    bf16x8 wf[4];
#pragma unroll
    for (int mi = 0; mi < 4; ++mi)
      wf[mi] = *(const bf16x8*)(Wc + (w * 4 + mi) * 1024 + l15 * 64 + lq * 16);
#pragma unroll
    for (int ni = 0; ni < 4; ++ni) {
      bf16x8 pf = *(const bf16x8*)(Qs + ni * 16384 + kc * 1024
                    + l15 * 64 + lq * 16);
#pragma unroll
      for (int mi = 0; mi < 4; ++mi)
        acc2[mi][ni] = __builtin_amdgcn_mfma_f32_16x16x32_bf16(wf[mi], pf, acc2[mi][ni], 0, 0, 0);
    }
    __syncthreads();  // W chunk kc+1 drained; all waves done with cur buffer
  }

  // epilogue: + bias + residual, store fp32 out[b][co][i0+i]
  const float* xb = x + (size_t)b * 524288;
  float* ob = out + (size_t)b * 524288;
#pragma unroll
  for (int mi = 0; mi < 4; ++mi) {
    int cbase = chb + mi * 16 + lq * 4;
    float4 bv = *(const float4*)&b_out[cbase];
    float bb[4] = {bv.x, bv.y, bv.z, bv.w};
#pragma unroll
    for (int ni = 0; ni < 4; ++ni) {
      int i = i0 + ni * 16 + l15;
#pragma unroll
      for (int r = 0; r < 4; ++r) {
        size_t off = (size_t)(cbase + r) * 1024 + i;
        ob[off] = acc2[mi][ni][r] + bb[r] + xb[off];
      }
    }
  }
}

extern "C" void kernel_launch(void* const* d_in, const int* in_sizes, int n_in,
                              void* d_out, int out_size, void* d_ws, size_t ws_size,
                              hipStream_t stream) {
  const float* x     = (const float*)d_in[0];
  const float* gamma = (const float*)d_in[1];
  const float* beta  = (const float*)d_in[2];
  const float* w_in  = (const float*)d_in[3];
  const float* b_in  = (const float*)d_in[4];
  const float* w_out = (const float*)d_in[5];
  const float* b_out = (const float*)d_in[6];
  float* out = (float*)d_out;

  char* w = (char*)d_ws;
  bf16* xn  = (bf16*)w;                              // 16 MB, token-major [b][hw][c]
  bf16* qk  = (bf16*)(w + ((size_t)16 << 20));       // 32 MB, [b][token][1024] (q|k)
  bf16* vcm = (bf16*)(w + ((size_t)48 << 20));       // 16 MB, [b][c][token]
  bf16* wib = (bf16*)(w + ((size_t)64 << 20));       // 1.5 MB
  bf16* wob = (bf16*)(w + ((size_t)64 << 20) + ((size_t)3 << 19));  // 0.5 MB

  cvt_w_kernel<<<1024, 256, 0, stream>>>(w_in, w_out, wib, wob);
  gn_kernel<<<NB * 32, 256, 0, stream>>>(x, gamma, beta, xn);

  // QK proj: M=1024 (o: q|k), N=1024 (token), K=512 -> qk[b][token][o]
  gemm_bt<0><<<dim3(8, 8, NB), 256, 0, stream>>>(
      wib, 512, 0, xn, 512, 512 * 1024, qk, 1024, 1024 * 1024, 512, b_in);
  // V proj: M=512 (c), N=1024 (token), K=512 -> vcm[b][c][token]
  gemm_bt<1><<<dim3(8, 4, NB), 256, 0, stream>>>(
      wib + 1024 * 512, 512, 0, xn, 512, 512 * 1024, vcm, 1024, 512 * 1024, 512,
      b_in + 1024);

  // fused attention: scores + softmax + PV + out-projection + residual
  flash_kernel<<<256, 512, 0, stream>>>(qk, vcm, wob, b_out, x, out);
}

// Round 11
// 142.939 us; speedup vs baseline: 1.0611x; 1.0611x over previous
//
#include <hip/hip_runtime.h>
#include <hip/hip_bf16.h>
#include <cstdint>
#include <cstddef>

#define HW   1024   // H*W tokens
#define NC   512    // channels
#define NB   16     // batch
#define EPSV 1e-5f

typedef __hip_bfloat16 bf16;
typedef __attribute__((ext_vector_type(8))) __bf16 bf16x8;
typedef __attribute__((ext_vector_type(4))) float f32x4;

__device__ __forceinline__ void gload16(const void* g, void* l) {
  __builtin_amdgcn_global_load_lds(
      (const __attribute__((address_space(1))) uint32_t*)g,
      (__attribute__((address_space(3))) uint32_t*)l, 16, 0, 0);
}

// ---------------- weight fp32 -> bf16 convert ----------------
// wib: linear [1536][512]. wob: FRAGMENT layout [chh 32][kc 16][co_lo 16][64B]
// where the 64B row holds the 32 c-values of the kc window linearly.
__global__ __launch_bounds__(256) void cvt_w_kernel(
    const float* __restrict__ wi, const float* __restrict__ wo,
    bf16* __restrict__ wib, char* __restrict__ wobf) {
  int i = blockIdx.x * 256 + threadIdx.x;
  if (i < 196608) {
    float4 v = ((const float4*)wi)[i];
    union { bf16 h[4]; uint2 u; } p;
    p.h[0] = __float2bfloat16(v.x); p.h[1] = __float2bfloat16(v.y);
    p.h[2] = __float2bfloat16(v.z); p.h[3] = __float2bfloat16(v.w);
    *(uint2*)&wib[(size_t)i * 4] = p.u;
  } else {
    int j = i - 196608;                   // 65536 float4s of w_out [512][512]
    float4 v = ((const float4*)wo)[j];
    int elem = j * 4;
    int co = elem >> 9, c = elem & 511;   // 4 consecutive c
    union { bf16 h[4]; uint2 u; } p;
    p.h[0] = __float2bfloat16(v.x); p.h[1] = __float2bfloat16(v.y);
    p.h[2] = __float2bfloat16(v.z); p.h[3] = __float2bfloat16(v.w);
    int chh = co >> 4, col_ = co & 15, kc = c >> 5, cc = c & 31;
    *(uint2*)(wobf + (((chh * 16 + kc) << 10) + col_ * 64 + cc * 2)) = p.u;
  }
}

// ---------------- GroupNorm -> xn token-major bf16 [b][hw][c] ----------------
__global__ __launch_bounds__(256) void gn_kernel(
    const float* __restrict__ x, const float* __restrict__ gamma,
    const float* __restrict__ beta, bf16* __restrict__ xn) {
  int blk = blockIdx.x;
  int b = blk >> 5, g = blk & 31;
  size_t base = ((size_t)(b * NC + g * 16)) * HW;
  const float4* src4 = (const float4*)(x + base);
  int t = threadIdx.x;
  float s = 0.f, ss = 0.f;
  float4 v[16];
#pragma unroll
  for (int i = 0; i < 16; ++i) {
    v[i] = src4[t + i * 256];
    s  += v[i].x + v[i].y + v[i].z + v[i].w;
    ss += v[i].x * v[i].x + v[i].y * v[i].y + v[i].z * v[i].z + v[i].w * v[i].w;
  }
  __shared__ float red[256];
  red[t] = s; __syncthreads();
  for (int o = 128; o > 0; o >>= 1) { if (t < o) red[t] += red[t + o]; __syncthreads(); }
  float mean = red[0] * (1.f / 16384.f);
  __syncthreads();
  red[t] = ss; __syncthreads();
  for (int o = 128; o > 0; o >>= 1) { if (t < o) red[t] += red[t + o]; __syncthreads(); }
  float var = red[0] * (1.f / 16384.f) - mean * mean;
  float rstd = rsqrtf(var + EPSV);

  __shared__ bf16 sm[16][1032];
#pragma unroll
  for (int i = 0; i < 16; ++i) {
    int idx = t + i * 256;
    int c = idx >> 8;
    int hw4 = (idx & 255) * 4;
    float gm = gamma[g * 16 + c], bt = beta[g * 16 + c];
    union { bf16 h[4]; uint2 u; } p;
    p.h[0] = __float2bfloat16((v[i].x - mean) * rstd * gm + bt);
    p.h[1] = __float2bfloat16((v[i].y - mean) * rstd * gm + bt);
    p.h[2] = __float2bfloat16((v[i].z - mean) * rstd * gm + bt);
    p.h[3] = __float2bfloat16((v[i].w - mean) * rstd * gm + bt);
    *(uint2*)&sm[c][hw4] = p.u;
  }
  __syncthreads();
  bf16* dst = xn + (size_t)b * HW * NC + g * 16;
#pragma unroll
  for (int it = 0; it < 8; ++it) {
    int u = it * 256 + t;
    int hw = u >> 1;
    int c8 = (u & 1) * 8;
    union { bf16 h[8]; uint4 q; } p;
#pragma unroll
    for (int j = 0; j < 8; ++j) p.h[j] = sm[c8 + j][hw];
    *(uint4*)&dst[(size_t)hw * NC + c8] = p.q;
  }
}

// ---------------- universal MFMA GEMM: C[M][N] = A[M][K] * B^T[N][K] --------
// MODE 0: bf16 store transposed  C[col*ldc+row], bias[row]   (q proj -> qtok)
// MODE 4: bf16 store K-fragment layout [tile 8][jg 8][kw 16][j_lo 16][64B]
// MODE 5: bf16 store V-fragment layout [tile 8][chh 32][ks 4][ch_lo 16][64B]
template <int MODE>
__global__ __launch_bounds__(256) void gemm_bt(
    const bf16* __restrict__ A, int lda, long long sA,
    const bf16* __restrict__ B, int ldb, long long sB,
    void* __restrict__ Cv, int ldc, long long sC,
    int K,
    const float* __restrict__ bias) {
  __shared__ bf16 sT[2][128][32];
  int z = blockIdx.z;
  const bf16* Ab = A + (size_t)z * sA;
  const bf16* Bb = B + (size_t)z * sB;
  int n0 = blockIdx.x * 128, m0 = blockIdx.y * 128;
  int t = threadIdx.x;
  int l = t & 63, w = t >> 6;
  int wm = w >> 1, wn = w & 1;

  int srow = t >> 2;
  int scol = (t & 3) * 8;

  f32x4 acc[4][4] = {};

  const bf16* ga0 = Ab + (size_t)(m0 + srow) * lda + scol;
  const bf16* gb0 = Bb + (size_t)(n0 + srow) * ldb + scol;

  for (int k0 = 0; k0 < K; k0 += 32) {
    gload16(ga0 + k0, &sT[0][srow][scol]);
    gload16(ga0 + (size_t)64 * lda + k0, &sT[0][64 + srow][scol]);
    gload16(gb0 + k0, &sT[1][srow][scol]);
    gload16(gb0 + (size_t)64 * ldb + k0, &sT[1][64 + srow][scol]);
    __syncthreads();
    bf16x8 af[4], bfr[4];
    int kc = (l >> 4) * 8;
    int ra = wm * 64 + (l & 15);
    int rb = wn * 64 + (l & 15);
#pragma unroll
    for (int i = 0; i < 4; ++i) {
      af[i]  = *(const bf16x8*)&sT[0][ra + i * 16][kc];
      bfr[i] = *(const bf16x8*)&sT[1][rb + i * 16][kc];
    }
#pragma unroll
    for (int i = 0; i < 4; ++i)
#pragma unroll
      for (int j = 0; j < 4; ++j)
        acc[i][j] = __builtin_amdgcn_mfma_f32_16x16x32_bf16(af[i], bfr[j], acc[i][j], 0, 0, 0);
    __syncthreads();
  }

  int rbase = (l >> 4) * 4;
#pragma unroll
  for (int i = 0; i < 4; ++i) {
    int row = m0 + wm * 64 + i * 16 + rbase;
    float4 bv = *(const float4*)&bias[row];
    float bb[4] = {bv.x, bv.y, bv.z, bv.w};
#pragma unroll
    for (int j = 0; j < 4; ++j) {
      int col = n0 + wn * 64 + j * 16 + (l & 15);
      if (MODE == 0) {
        bf16* C = (bf16*)Cv + (size_t)z * sC;
        union { bf16 h[4]; uint2 u; } p;
#pragma unroll
        for (int r = 0; r < 4; ++r) p.h[r] = __float2bfloat16(acc[i][j][r] + bb[r]);
        *(uint2*)&C[(size_t)col * ldc + row] = p.u;
      } else if (MODE == 4) {
        char* C = (char*)Cv + (size_t)z * sC * 2;
        int tile = col >> 7, jgc = (col >> 4) & 7, j_lo = col & 15;
        int kw = row >> 5, cc = row & 31;   // cc multiple of 4
        union { bf16 h[4]; uint2 u; } p;
#pragma unroll
        for (int r = 0; r < 4; ++r) p.h[r] = __float2bfloat16(acc[i][j][r] + bb[r]);
        *(uint2*)(C + (((tile * 8 + jgc) * 16 + kw) << 10) + j_lo * 64 + cc * 2) = p.u;
      } else {  // MODE 5
        char* C = (char*)Cv + (size_t)z * sC * 2;
        int tile = col >> 7, jj = col & 127;
        int ks = jj >> 5, jc = jj & 31;
#pragma unroll
        for (int r = 0; r < 4; ++r) {
          int ch = row + r;
          int chh = ch >> 4, chl = ch & 15;
          *(bf16*)(C + (((tile * 32 + chh) * 4 + ks) << 10)
                     + chl * 64 + jc * 2) = __float2bfloat16(acc[i][j][r] + bb[r]);
        }
      }
    }
  }
}

// ---------------- fused flash attention + out-projection ----------------
// grid: 256 wg, 512 threads (8 waves). KVBLK=128, 8 KV tiles, 1 barrier/tile.
// K,V,W read DIRECTLY from global in fragment-linear layout: each wave reads
// a contiguous 1KB block; lane l takes bytes l15*64 + lq*16 (row l15, c-window
// lq) — dense 16x64B lines, L2-resident, XCD-pinned.
// LDS: Qs 64KB subtiled + P dbuf 2x16KB.
__global__ __launch_bounds__(512, 1) void flash_kernel(
    const bf16* __restrict__ qtok, const bf16* __restrict__ kfrag,
    const bf16* __restrict__ vfrag, const bf16* __restrict__ wfrag,
    const float* __restrict__ b_out, const float* __restrict__ x,
    float* __restrict__ out) {
  __shared__ char lds[98304];
  char* Qs = lds;                        // 64KB: [ih2 4][ks 16][i_lo 16][64B]
  char* Ps = lds + 65536;                // 2 x 16KB: [ni 4][js 4][i_lo 16][64B]
  float* redl = (float*)(lds + 65536);   // epilogue overlay (2KB, Ps dead)

  int id = blockIdx.x;
  int xcd = id & 7, rest = id >> 3;
  int q = rest & 15, bh = rest >> 4;
  int b = xcd + bh * 8;                  // batch -> fixed XCD (K/V L2 locality)
  int i0 = q * 64;

  const char* qC = (const char*)qtok + (size_t)b * 1048576;   // [1024 tok][512]
  const char* kC = (const char*)kfrag + (size_t)b * 1048576;  // frag layout
  const char* vC = (const char*)vfrag + (size_t)b * 1048576;  // frag layout
  const char* wC = (const char*)wfrag;                        // frag layout

  int t = threadIdx.x, l = t & 63, w = t >> 6;
  int l15 = l & 15, lq = l >> 4;
  int fofs = l15 * 64 + lq * 16;         // fragment byte offset (row l15, lq)
  int chb = w * 64;

  // ---- prologue: stage Q subtiled
#pragma unroll
  for (int it = 0; it < 8; ++it) {
    int A = it * 8192 + t * 16;
    int ih2 = A >> 14, ks = (A >> 10) & 15, ilo = (A >> 6) & 15, cb = A & 63;
    gload16(qC + (size_t)(i0 + ih2 * 16 + ilo) * 1024 + ks * 64 + cb, Qs + A);
  }

  float lacc[4] = {0.f, 0.f, 0.f, 0.f};
  f32x4 o[4][4] = {};                        // [mi: ch frag][ni: i frag]
  const float scl = 0.044194173824159216f;   // 1/sqrt(512)

  __syncthreads();   // Q staged

  for (int tile = 0; tile < 8; ++tile) {
    char* Pc = Ps + (tile & 1) * 16384;
    // issue V fragment loads early (consumed after the barrier)
    bf16x8 vf[4][4];
#pragma unroll
    for (int ks = 0; ks < 4; ++ks)
#pragma unroll
      for (int mi = 0; mi < 4; ++mi)
        vf[ks][mi] = *(const bf16x8*)(vC
            + (((size_t)(tile * 32 + (w * 4 + mi)) * 4 + ks) << 10) + fofs);
    // ---- QK^T: S^T[16 j][64 i], K fragments direct from L2, Q from LDS
    f32x4 s[4] = {};
#pragma unroll
    for (int kw = 0; kw < 16; ++kw) {
      bf16x8 kf = *(const bf16x8*)(kC
          + (((size_t)(tile * 8 + w) * 16 + kw) << 10) + fofs);
#pragma unroll
      for (int ni = 0; ni < 4; ++ni) {
        bf16x8 qf = *(const bf16x8*)(Qs + ni * 16384 + kw * 1024 + fofs);
        s[ni] = __builtin_amdgcn_mfma_f32_16x16x32_bf16(kf, qf, s[ni], 0, 0, 0);
      }
    }
    // ---- P = exp(s*scl) (no max subtraction), pack into P[cur]
#pragma unroll
    for (int ni = 0; ni < 4; ++ni) {
      float p0 = __expf(s[ni][0] * scl);
      float p1 = __expf(s[ni][1] * scl);
      float p2 = __expf(s[ni][2] * scl);
      float p3 = __expf(s[ni][3] * scl);
      lacc[ni] += p0 + p1 + p2 + p3;
      union { bf16 h[4]; uint64_t u; } pk;
      pk.h[0] = __float2bfloat16(p0); pk.h[1] = __float2bfloat16(p1);
      pk.h[2] = __float2bfloat16(p2); pk.h[3] = __float2bfloat16(p3);
      // j = w*16 + lq*4 + r -> js = w>>1, byte = (w&1)*32 + lq*8
      *(uint64_t*)(Pc + ni * 4096 + (w >> 1) * 1024 + l15 * 64
                   + (w & 1) * 32 + lq * 8) = pk.u;
    }
    __syncthreads();   // the ONLY barrier in the tile loop
    // ---- PV: O^T[64 ch][64 i] += V^T x P
#pragma unroll
    for (int ks = 0; ks < 4; ++ks)
#pragma unroll
      for (int ni = 0; ni < 4; ++ni) {
        bf16x8 pf = *(const bf16x8*)(Pc + ni * 4096 + ks * 1024 + fofs);
#pragma unroll
        for (int mi = 0; mi < 4; ++mi)
          o[mi][ni] = __builtin_amdgcn_mfma_f32_16x16x32_bf16(vf[ks][mi], pf, o[mi][ni], 0, 0, 0);
      }
  }

  // ---- row-sum combine (redl overlays dead Ps[0])
#pragma unroll
  for (int ni = 0; ni < 4; ++ni) {
    float v = lacc[ni];
    v += __shfl_xor(v, 16);
    v += __shfl_xor(v, 32);
    if (l < 16) redl[w * 64 + ni * 16 + l] = v;
  }
  __syncthreads();
  float linv[4];
#pragma unroll
  for (int ni = 0; ni < 4; ++ni) {
    int i = ni * 16 + l15;
    float v = redl[i];
#pragma unroll
    for (int w2 = 1; w2 < 8; ++w2) v += redl[w2 * 64 + i];
    linv[ni] = 1.f / v;
  }
  // normalized O -> ao_lds subtiled [ni 4][kc 16][i_lo 16][64B] over dead Qs
#pragma unroll
  for (int mi = 0; mi < 4; ++mi)
#pragma unroll
    for (int ni = 0; ni < 4; ++ni) {
      union { bf16 h[4]; uint64_t u; } pk;
#pragma unroll
      for (int r = 0; r < 4; ++r)
        pk.h[r] = __float2bfloat16(o[mi][ni][r] * linv[ni]);
      int dst = ni * 16384 + (w * 2 + (mi >> 1)) * 1024 + l15 * 64
              + (mi & 1) * 32 + lq * 8;
      *(uint64_t*)(Qs + dst) = pk.u;
    }
  __syncthreads();  // ao_lds ready

  // ---- out-projection: W fragments direct from L2; no barriers in loop
  f32x4 acc2[4][4] = {};
#pragma unroll
  for (int kc = 0; kc < 16; ++kc) {
    bf16x8 wf[4];
#pragma unroll
    for (int mi = 0; mi < 4; ++mi)
      wf[mi] = *(const bf16x8*)(wC + (((size_t)(w * 4 + mi) * 16 + kc) << 10) + fofs);
#pragma unroll
    for (int ni = 0; ni < 4; ++ni) {
      bf16x8 pf = *(const bf16x8*)(Qs + ni * 16384 + kc * 1024 + fofs);
#pragma unroll
      for (int mi = 0; mi < 4; ++mi)
        acc2[mi][ni] = __builtin_amdgcn_mfma_f32_16x16x32_bf16(wf[mi], pf, acc2[mi][ni], 0, 0, 0);
    }
  }

  // epilogue: + bias + residual, store fp32 out[b][co][i0+i]
  const float* xb = x + (size_t)b * 524288;
  float* ob = out + (size_t)b * 524288;
#pragma unroll
  for (int mi = 0; mi < 4; ++mi) {
    int cbase = chb + mi * 16 + lq * 4;
    float4 bv = *(const float4*)&b_out[cbase];
    float bb[4] = {bv.x, bv.y, bv.z, bv.w};
#pragma unroll
    for (int ni = 0; ni < 4; ++ni) {
      int i = i0 + ni * 16 + l15;
#pragma unroll
      for (int r = 0; r < 4; ++r) {
        size_t off = (size_t)(cbase + r) * 1024 + i;
        ob[off] = acc2[mi][ni][r] + bb[r] + xb[off];
      }
    }
  }
}

extern "C" void kernel_launch(void* const* d_in, const int* in_sizes, int n_in,
                              void* d_out, int out_size, void* d_ws, size_t ws_size,
                              hipStream_t stream) {
  const float* x     = (const float*)d_in[0];
  const float* gamma = (const float*)d_in[1];
  const float* beta  = (const float*)d_in[2];
  const float* w_in  = (const float*)d_in[3];
  const float* b_in  = (const float*)d_in[4];
  const float* w_out = (const float*)d_in[5];
  const float* b_out = (const float*)d_in[6];
  float* out = (float*)d_out;

  char* w = (char*)d_ws;
  bf16* xn    = (bf16*)w;                              // 16 MB token-major
  bf16* qtok  = (bf16*)(w + ((size_t)16 << 20));       // 16 MB [b][tok][512]
  bf16* kfrag = (bf16*)(w + ((size_t)32 << 20));       // 16 MB fragment layout
  bf16* vfrag = (bf16*)(w + ((size_t)48 << 20));       // 16 MB fragment layout
  bf16* wib   = (bf16*)(w + ((size_t)64 << 20));       // 1.5 MB
  char* wobf  = (char*)(w + ((size_t)64 << 20) + ((size_t)3 << 19));  // 0.5 MB

  cvt_w_kernel<<<1024, 256, 0, stream>>>(w_in, w_out, wib, wobf);
  gn_kernel<<<NB * 32, 256, 0, stream>>>(x, gamma, beta, xn);

  // q proj: M=512, N=1024 tok, K=512 -> qtok[b][tok][512] (transposed store)
  gemm_bt<0><<<dim3(8, 4, NB), 256, 0, stream>>>(
      wib, 512, 0, xn, 512, 512 * 1024, qtok, 512, 512 * 1024, 512, b_in);
  // k proj -> K fragment layout
  gemm_bt<4><<<dim3(8, 4, NB), 256, 0, stream>>>(
      wib + 512 * 512, 512, 0, xn, 512, 512 * 1024, kfrag, 0, 512 * 1024, 512,
      b_in + 512);
  // v proj -> V fragment layout
  gemm_bt<5><<<dim3(8, 4, NB), 256, 0, stream>>>(
      wib + 1024 * 512, 512, 0, xn, 512, 512 * 1024, vfrag, 0, 512 * 1024, 512,
      b_in + 1024);

  // fused attention + out projection + residual
  flash_kernel<<<256, 512, 0, stream>>>(qtok, kfrag, vfrag, (const bf16*)wobf,
                                        b_out, x, out);
}